// Round 3
// baseline (415.183 us; speedup 1.0000x reference)
//
#include <hip/hip_runtime.h>
#include <math.h>

#define KCLS  50000
#define KP    50048   // KCLS padded to multiple of 128 for the GEMM class dim
#define NBLK  (KP / 128)   // 391 column blocks
#define NSTR  392          // partial row stride (float2 units)
#define DIM   128
#define BATCH 1024
#define MAXD  16

typedef __attribute__((ext_vector_type(8))) short short8;
typedef __attribute__((ext_vector_type(4))) float floatx4;

// round-to-nearest-even float -> bf16 bits (inputs are finite)
__device__ __forceinline__ unsigned short f2bf(float f) {
    unsigned u = __float_as_uint(f);
    u += 0x7fffu + ((u >> 16) & 1u);
    return (unsigned short)(u >> 16);
}

// ---------------------------------------------------------------------------
// Kernel 1: added_weights[k] = weights[k] + sum_{p<len} weights[path_idx[k,p]]
// 8 classes per 256-thread block; 32 lanes x float4 per class row.
// Also emits the bf16 copy (padded to KP rows, pad rows zeroed) for the MFMA GEMM.
__global__ __launch_bounds__(256) void aw_kernel(
    const float* __restrict__ weights, const int* __restrict__ path_idx,
    const int* __restrict__ path_len, float* __restrict__ aw,
    unsigned short* __restrict__ awb)
{
    int t = threadIdx.x;
    int c = t >> 5;            // 0..7 local class
    int lane = t & 31;
    int k = blockIdx.x * 8 + c;
    int col = lane * 4;

    if (k >= KCLS) {           // zero-fill bf16 pad rows [KCLS, KP)
        ushort4 z = {0, 0, 0, 0};
        *(ushort4*)(awb + (size_t)k * DIM + col) = z;
        return;
    }

    float4 acc = *(const float4*)(weights + (size_t)k * DIM + col);
    int len = path_len[k];
    const int* pp = path_idx + (size_t)k * MAXD;
    for (int p = 0; p < len; ++p) {
        int idx = pp[p];
        float4 wv = *(const float4*)(weights + (size_t)idx * DIM + col);
        acc.x += wv.x; acc.y += wv.y; acc.z += wv.z; acc.w += wv.w;
    }
    *(float4*)(aw + (size_t)k * DIM + col) = acc;
    ushort4 hv = { f2bf(acc.x), f2bf(acc.y), f2bf(acc.z), f2bf(acc.w) };
    *(ushort4*)(awb + (size_t)k * DIM + col) = hv;
}

// ---------------------------------------------------------------------------
// x fp32 -> bf16  (1024*128 = 131072 elements, 4 per thread)
__global__ __launch_bounds__(256) void xconv_kernel(
    const float* __restrict__ x, unsigned short* __restrict__ xb)
{
    int i = (blockIdx.x * 256 + threadIdx.x) * 4;
    float4 v = *(const float4*)(x + i);
    ushort4 hv = { f2bf(v.x), f2bf(v.y), f2bf(v.z), f2bf(v.w) };
    *(ushort4*)(xb + i) = hv;
}

// ---------------------------------------------------------------------------
// Kernel 2: logits = Xb · Wb^T via bf16 MFMA 16x16x32, with fused per-block
// softmax partials. 128x128 block tile, 4 waves in 2x2, each wave 64x64.
// Both operands row-major [.][128] -> every fragment is one contiguous 16B
// global load (no LDS in the main loop, no transpose). K=128 fully unrolled.
// Epilogue: per row of the block, compute max and sum(exp(v-max)) over the
// 128 columns (pad cols masked to -inf) and write one float2 partial.
__global__ __launch_bounds__(256) void gemm_kernel(
    const unsigned short* __restrict__ Xb,   // [BATCH][DIM] bf16
    const unsigned short* __restrict__ Wb,   // [KP][DIM] bf16
    float* __restrict__ logits,              // [BATCH][KCLS]
    float2* __restrict__ partials)           // [BATCH][NSTR]
{
    int tid = threadIdx.x;
    int wave = tid >> 6, lane = tid & 63;
    int r = lane & 15, quad = lane >> 4;
    int m0 = blockIdx.y * 128 + (wave >> 1) * 64;
    int n0 = blockIdx.x * 128 + (wave & 1) * 64;

    const unsigned short* ap = Xb + (size_t)(m0 + r) * DIM + quad * 8;
    const unsigned short* bp = Wb + (size_t)(n0 + r) * DIM + quad * 8;

    floatx4 acc[4][4];
    #pragma unroll
    for (int i = 0; i < 4; ++i)
        #pragma unroll
        for (int j = 0; j < 4; ++j)
            acc[i][j] = (floatx4){0.f, 0.f, 0.f, 0.f};

    #pragma unroll
    for (int kk = 0; kk < 4; ++kk) {
        short8 a[4], b[4];
        #pragma unroll
        for (int i = 0; i < 4; ++i)
            a[i] = *(const short8*)(ap + (size_t)(i * 16) * DIM + kk * 32);
        #pragma unroll
        for (int j = 0; j < 4; ++j)
            b[j] = *(const short8*)(bp + (size_t)(j * 16) * DIM + kk * 32);
        #pragma unroll
        for (int i = 0; i < 4; ++i)
            #pragma unroll
            for (int j = 0; j < 4; ++j)
                acc[i][j] = __builtin_amdgcn_mfma_f32_16x16x32_bf16(
                    a[i], b[j], acc[i][j], 0, 0, 0);
    }

    // ---- store logits (pad cols masked) ----
    #pragma unroll
    for (int i = 0; i < 4; ++i) {
        int mrow = m0 + i * 16 + quad * 4;
        #pragma unroll
        for (int j = 0; j < 4; ++j) {
            int col = n0 + j * 16 + r;
            if (col < KCLS) {
                float* cp = logits + (size_t)mrow * KCLS + col;
                #pragma unroll
                for (int reg = 0; reg < 4; ++reg)
                    cp[(size_t)reg * KCLS] = acc[i][j][reg];
            }
        }
    }

    // ---- fused softmax partials over this block's 128 columns ----
    // valid-column mask per j (depends only on lane's r)
    bool ok[4];
    #pragma unroll
    for (int j = 0; j < 4; ++j) ok[j] = (n0 + j * 16 + r) < KCLS;

    __shared__ float2 part[128][2];   // [row in block][n-half]
    int halfn = wave & 1;
    int rowbase = (wave >> 1) * 64;

    #pragma unroll
    for (int i = 0; i < 4; ++i) {
        #pragma unroll
        for (int reg = 0; reg < 4; ++reg) {
            float v0 = ok[0] ? acc[i][0][reg] : -INFINITY;
            float v1 = ok[1] ? acc[i][1][reg] : -INFINITY;
            float v2 = ok[2] ? acc[i][2][reg] : -INFINITY;
            float v3 = ok[3] ? acc[i][3][reg] : -INFINITY;
            float m = fmaxf(fmaxf(v0, v1), fmaxf(v2, v3));
            #pragma unroll
            for (int msk = 1; msk < 16; msk <<= 1)
                m = fmaxf(m, __shfl_xor(m, msk));
            float s = __expf(v0 - m) + __expf(v1 - m)
                    + __expf(v2 - m) + __expf(v3 - m);
            #pragma unroll
            for (int msk = 1; msk < 16; msk <<= 1)
                s += __shfl_xor(s, msk);
            if (r == 0)
                part[rowbase + i * 16 + quad * 4 + reg][halfn] = make_float2(m, s);
        }
    }
    __syncthreads();

    if (tid < 128) {
        float2 p0 = part[tid][0];
        float2 p1 = part[tid][1];
        float M = fmaxf(p0.x, p1.x);
        float S = p0.y * __expf(p0.x - M) + p1.y * __expf(p1.x - M);
        partials[(size_t)(blockIdx.y * 128 + tid) * NSTR + blockIdx.x]
            = make_float2(M, S);
    }
}

// ---------------------------------------------------------------------------
// Kernel 3: merge per-block partials -> lse per row -> loss. One wave per row.
__global__ __launch_bounds__(64) void finalize_kernel(
    const float2* __restrict__ partials, const float* __restrict__ logits,
    const int* __restrict__ y, float* __restrict__ loss)
{
    int b = blockIdx.x;
    const float2* row = partials + (size_t)b * NSTR;
    float m = -INFINITY, s = 0.f;
    for (int i = threadIdx.x; i < NBLK; i += 64) {
        float2 p = row[i];
        float M = fmaxf(m, p.x);
        s = s * __expf(m - M) + p.y * __expf(p.x - M);
        m = M;
    }
    #pragma unroll
    for (int off = 32; off > 0; off >>= 1) {
        float m2 = __shfl_down(m, off);
        float s2 = __shfl_down(s, off);
        float M = fmaxf(m, m2);
        s = s * __expf(m - M) + s2 * __expf(m2 - M);
        m = M;
    }
    if (threadIdx.x == 0) {
        float lse = m + __logf(s);
        float ly = logits[(size_t)b * KCLS + y[b]];
        atomicAdd(loss, (lse - ly) * (1.0f / BATCH));
    }
}

// ---------------------------------------------------------------------------
extern "C" void kernel_launch(void* const* d_in, const int* in_sizes, int n_in,
                              void* d_out, int out_size, void* d_ws, size_t ws_size,
                              hipStream_t stream)
{
    const float* weights  = (const float*)d_in[0];   // [65536][128]
    const float* x        = (const float*)d_in[1];   // [1024][128]
    const int*   y        = (const int*)d_in[2];     // [1024]
    const int*   path_idx = (const int*)d_in[3];     // [50000][16]
    const int*   path_len = (const int*)d_in[4];     // [50000]

    float* out    = (float*)d_out;
    float* loss   = out;                                  // [1]
    float* logits = out + 1;                              // [1024][50000]
    float* aw     = out + 1 + (size_t)BATCH * KCLS;       // [50000][128]

    unsigned short* awb = (unsigned short*)d_ws;          // [KP][128] bf16
    unsigned short* xb  = awb + (size_t)KP * DIM;         // [1024][128] bf16
    float2* partials = (float2*)(xb + (size_t)BATCH * DIM); // [1024][NSTR]

    hipMemsetAsync(loss, 0, sizeof(float), stream);

    aw_kernel<<<KP / 8, 256, 0, stream>>>(weights, path_idx, path_len, aw, awb);
    xconv_kernel<<<BATCH * DIM / 1024, 256, 0, stream>>>(x, xb);

    gemm_kernel<<<dim3(NBLK, BATCH / 128), 256, 0, stream>>>(xb, awb, logits, partials);

    finalize_kernel<<<BATCH, 64, 0, stream>>>(partials, logits, y, loss);
}